// Round 7
// baseline (573.552 us; speedup 1.0000x reference)
//
#include <hip/hip_runtime.h>

#define NN 50000
#define NE 800000
#define NG 1000
#define DIN 64
#define HIDC 64
#define GOUTC 256
#define FPC 2048
#define H1C 1024
#define H2C 512
#define MOUTC 256
#define D1C 512
#define EPSV 1e-5f
#define SLOPEV 0.2f

typedef __attribute__((ext_vector_type(8))) short s8v;
typedef __attribute__((ext_vector_type(4))) float f4v;
typedef unsigned short ushort_t;

__device__ inline ushort_t f2b(float f) {
    unsigned u = __builtin_bit_cast(unsigned, f);
    unsigned r = (u + 0x7FFFu + ((u >> 16) & 1u)) >> 16;
    return (ushort_t)r;
}
__device__ inline float b2f(ushort_t u) {
    return __builtin_bit_cast(float, ((unsigned)u) << 16);
}

// ---- GAT: xl_bf = bf16(x @ Wg^T) ; a_src = xl.att_src ; a_dst = xl.att_dst ----
__global__ void k_xl(const float* __restrict__ x, const float* __restrict__ Wg,
                     const float* __restrict__ att_src, const float* __restrict__ att_dst,
                     ushort_t* __restrict__ xl_bf, float* __restrict__ a_src,
                     float* __restrict__ a_dst) {
    __shared__ float Wgs[64][65];
    __shared__ float xs[4][64];
    int t = threadIdx.x;
    int lane = t & 63;
    int w = t >> 6;
    for (int i = t; i < 64 * 64; i += 256) Wgs[i >> 6][i & 63] = Wg[i];
    int node = blockIdx.x * 4 + w;
    xs[w][lane] = x[node * 64 + lane];
    __syncthreads();
    float acc = 0.f;
#pragma unroll
    for (int d = 0; d < 64; ++d) acc += xs[w][d] * Wgs[lane][d];
    xl_bf[node * 64 + lane] = f2b(acc);
    float vs = acc * att_src[lane];
    float vd = acc * att_dst[lane];
#pragma unroll
    for (int off = 32; off > 0; off >>= 1) {
        vs += __shfl_xor(vs, off);
        vd += __shfl_xor(vd, off);
    }
    if (lane == 0) { a_src[node] = vs; a_dst[node] = vd; }
}

// ---- CSR build: degree histogram ----
__global__ void k_deg(const int* __restrict__ ei, int* __restrict__ deg) {
    int e = blockIdx.x * 256 + threadIdx.x;
    if (e < NE) atomicAdd(&deg[ei[NE + e]], 1);
}

// ---- CSR build: single-block exclusive scan of deg -> rowptr, cursor ----
__global__ __launch_bounds__(1024) void k_scan(const int* __restrict__ deg,
                                               int* __restrict__ rowptr,
                                               int* __restrict__ cursor) {
    __shared__ int part[1024];
    int t = threadIdx.x;
    const int CH = (NN + 1023) / 1024;  // 49
    int base = t * CH;
    int s = 0;
    for (int i = 0; i < CH; ++i) {
        int idx = base + i;
        if (idx < NN) s += deg[idx];
    }
    part[t] = s;
    __syncthreads();
    for (int off = 1; off < 1024; off <<= 1) {
        int v = (t >= off) ? part[t - off] : 0;
        __syncthreads();
        part[t] += v;
        __syncthreads();
    }
    int run = (t == 0) ? 0 : part[t - 1];
    for (int i = 0; i < CH; ++i) {
        int idx = base + i;
        if (idx < NN) {
            rowptr[idx] = run;
            cursor[idx] = run;
            run += deg[idx];
        }
    }
}

// ---- CSR build: scatter src indices by dst ----
__global__ void k_scatter(const int* __restrict__ ei, int* __restrict__ cursor,
                          int* __restrict__ csr_src) {
    int e = blockIdx.x * 256 + threadIdx.x;
    if (e < NE) {
        int d = ei[NE + e];
        int pos = atomicAdd(&cursor[d], 1);
        csr_src[pos] = ei[e];
    }
}

// ---- fused gather: softmax-weighted aggregation + bias + relu + mean-pool ----
__global__ void k_gather(const int* __restrict__ csr_src, const int* __restrict__ rowptr,
                         const int* __restrict__ deg, const ushort_t* __restrict__ xl_bf,
                         const float* __restrict__ a_src, const float* __restrict__ a_dst,
                         const float* __restrict__ gat_bias, const int* __restrict__ batch,
                         float* __restrict__ gsum, int* __restrict__ gcnt) {
    int t = threadIdx.x, lane = t & 63, w = t >> 6;
    int n = blockIdx.x * 4 + w;
    float ad = a_dst[n];
    // self loop
    float ev = a_src[n] + ad;
    ev = ev > 0.f ? ev : SLOPEV * ev;
    float ex = expf(ev);
    float den = ex;
    float acc = ex * b2f(xl_bf[(size_t)n * 64 + lane]);
    int beg = rowptr[n];
    int end = beg + deg[n];
    int j = beg;
    for (; j + 4 <= end; j += 4) {
        int s0 = csr_src[j], s1 = csr_src[j + 1], s2 = csr_src[j + 2], s3 = csr_src[j + 3];
        float e0 = a_src[s0] + ad, e1 = a_src[s1] + ad, e2 = a_src[s2] + ad, e3 = a_src[s3] + ad;
        e0 = e0 > 0.f ? e0 : SLOPEV * e0;
        e1 = e1 > 0.f ? e1 : SLOPEV * e1;
        e2 = e2 > 0.f ? e2 : SLOPEV * e2;
        e3 = e3 > 0.f ? e3 : SLOPEV * e3;
        float x0 = expf(e0), x1 = expf(e1), x2 = expf(e2), x3 = expf(e3);
        float v0 = b2f(xl_bf[(size_t)s0 * 64 + lane]);
        float v1 = b2f(xl_bf[(size_t)s1 * 64 + lane]);
        float v2 = b2f(xl_bf[(size_t)s2 * 64 + lane]);
        float v3 = b2f(xl_bf[(size_t)s3 * 64 + lane]);
        den += x0 + x1 + x2 + x3;
        acc += x0 * v0;
        acc += x1 * v1;
        acc += x2 * v2;
        acc += x3 * v3;
    }
    for (; j < end; ++j) {
        int s0 = csr_src[j];
        float e0 = a_src[s0] + ad;
        e0 = e0 > 0.f ? e0 : SLOPEV * e0;
        float x0 = expf(e0);
        den += x0;
        acc += x0 * b2f(xl_bf[(size_t)s0 * 64 + lane]);
    }
    float v = acc / den + gat_bias[lane];
    v = v > 0.f ? v : 0.f;
    int b = batch[n];
    atomicAdd(&gsum[b * 64 + lane], v);
    if (lane == 0) atomicAdd(&gcnt[b], 1);
}

__global__ void k_pooled(const float* __restrict__ gsum, const int* __restrict__ gcnt,
                         ushort_t* __restrict__ pooled_bf) {
    int i = blockIdx.x * 256 + threadIdx.x;
    if (i < NG * 64) {
        float c = (float)gcnt[i >> 6];
        pooled_bf[i] = f2b(gsum[i] / fmaxf(c, 1.f));
    }
}

// ---- fp32 -> bf16 conversion (8 elems/thread) ----
__global__ void k_f2b(const float* __restrict__ s, ushort_t* __restrict__ d, int n) {
    int i = (blockIdx.x * 256 + threadIdx.x) * 8;
    if (i + 8 <= n) {
#pragma unroll
        for (int j = 0; j < 8; ++j) d[i + j] = f2b(s[i + j]);
    } else {
        for (int j = i; j < n; ++j) d[j] = f2b(s[j]);
    }
}

// ---- bf16 MFMA GEMM: C[M,N](ldc) = A[M,K]bf16 @ B[N,K]bf16^T + bias ----
template <bool RELU, bool OBF16>
__global__ __launch_bounds__(256) void k_mgemm(const ushort_t* __restrict__ A,
                                               const ushort_t* __restrict__ B,
                                               const float* __restrict__ bias, void* Cv,
                                               int M, int N, int K, int ldc) {
    __shared__ ushort_t As[64][40];
    __shared__ ushort_t Bs[64][40];
    int t = threadIdx.x;
    int lane = t & 63, w = t >> 6;
    int wr = w >> 1, wc = w & 1;
    int bm = blockIdx.y * 64, bn = blockIdx.x * 64;
    f4v acc[2][2];
#pragma unroll
    for (int m = 0; m < 2; ++m)
#pragma unroll
        for (int n = 0; n < 2; ++n) acc[m][n] = (f4v){0.f, 0.f, 0.f, 0.f};

    int lr = t >> 2;
    int lk = (t & 3) * 8;
    int arow = bm + lr;
    bool aval = arow < M;
    const ushort_t* aptr = A + (size_t)(aval ? arow : (M - 1)) * K + lk;
    const ushort_t* bptr = B + (size_t)(bn + lr) * K + lk;
    int fr = lane & 15, kg = lane >> 4;

    for (int k0 = 0; k0 < K; k0 += 32) {
        s8v av = {};
        if (aval) av = *(const s8v*)(aptr + k0);
        s8v bv = *(const s8v*)(bptr + k0);
        *(s8v*)&As[lr][lk] = av;
        *(s8v*)&Bs[lr][lk] = bv;
        __syncthreads();
        s8v bfrag0 = *(const s8v*)&Bs[wc * 32 + 0 * 16 + fr][kg * 8];
        s8v bfrag1 = *(const s8v*)&Bs[wc * 32 + 1 * 16 + fr][kg * 8];
#pragma unroll
        for (int m = 0; m < 2; ++m) {
            s8v af = *(const s8v*)&As[wr * 32 + m * 16 + fr][kg * 8];
            acc[m][0] = __builtin_amdgcn_mfma_f32_16x16x32_bf16(af, bfrag0, acc[m][0], 0, 0, 0);
            acc[m][1] = __builtin_amdgcn_mfma_f32_16x16x32_bf16(af, bfrag1, acc[m][1], 0, 0, 0);
        }
        __syncthreads();
    }
    int fq = lane >> 4;
#pragma unroll
    for (int m = 0; m < 2; ++m) {
        int row = bm + wr * 32 + m * 16 + fq * 4;
#pragma unroll
        for (int n = 0; n < 2; ++n) {
            int col = bn + wc * 32 + n * 16 + fr;
            float bb = bias[col];
#pragma unroll
            for (int r = 0; r < 4; ++r) {
                int gr = row + r;
                if (gr < M) {
                    float v = acc[m][n][r] + bb;
                    if (RELU) v = fmaxf(v, 0.f);
                    if (OBF16) ((ushort_t*)Cv)[(size_t)gr * ldc + col] = f2b(v);
                    else ((float*)Cv)[(size_t)gr * ldc + col] = v;
                }
            }
        }
    }
}

// ---- BN: row-split partial sums -> finalize -> normalize(+relu)+bf16 ----
__global__ void k_bnpart(const float* __restrict__ h, float* __restrict__ sum,
                         float* __restrict__ sumsq, int ncols) {
    int col = blockIdx.x * 256 + threadIdx.x;
    int r0 = blockIdx.y * 125;
    float s = 0.f, q = 0.f;
    for (int r = r0; r < r0 + 125; ++r) {
        float v = h[(size_t)r * ncols + col];
        s += v;
        q += v * v;
    }
    atomicAdd(&sum[col], s);
    atomicAdd(&sumsq[col], q);
}

__global__ void k_bnfin(const float* __restrict__ sum, const float* __restrict__ sumsq,
                        const float* __restrict__ gamma, const float* __restrict__ beta,
                        float* __restrict__ scale, float* __restrict__ shift, int ncols) {
    int col = blockIdx.x * 256 + threadIdx.x;
    if (col >= ncols) return;
    float mu = sum[col] * (1.f / NG);
    float var = sumsq[col] * (1.f / NG) - mu * mu;
    float rstd = rsqrtf(var + EPSV);
    float sc = gamma[col] * rstd;
    scale[col] = sc;
    shift[col] = beta[col] - mu * sc;
}

__global__ void k_bnrelu_bf(const float* __restrict__ h, const float* __restrict__ scale,
                            const float* __restrict__ shift, ushort_t* __restrict__ dst,
                            int colmask, int total) {
    int i = (blockIdx.x * 256 + threadIdx.x) * 4;
    if (i < total) {
#pragma unroll
        for (int j = 0; j < 4; ++j) {
            int col = (i + j) & colmask;
            float v = h[i + j] * scale[col] + shift[col];
            dst[i + j] = f2b(fmaxf(v, 0.f));
        }
    }
}

// ---- final: out[g] = sum_j (z[g,j]*scale[j]+shift[j]) * Wl[j] + bl ----
__global__ void k_final(const float* __restrict__ z, const float* __restrict__ scale,
                        const float* __restrict__ shift, const float* __restrict__ Wl,
                        const float* __restrict__ bl, float* __restrict__ out) {
    int g = blockIdx.x;
    int t = threadIdx.x;
    float acc = 0.f;
    for (int j = t; j < D1C; j += 256) {
        float v = z[g * D1C + j] * scale[j] + shift[j];
        acc += v * Wl[j];
    }
#pragma unroll
    for (int off = 32; off > 0; off >>= 1) acc += __shfl_xor(acc, off);
    __shared__ float red[4];
    int lane = t & 63, w = t >> 6;
    if (lane == 0) red[w] = acc;
    __syncthreads();
    if (t == 0) out[g] = red[0] + red[1] + red[2] + red[3] + bl[0];
}

extern "C" void kernel_launch(void* const* d_in, const int* in_sizes, int n_in,
                              void* d_out, int out_size, void* d_ws, size_t ws_size,
                              hipStream_t stream) {
    const float* x       = (const float*)d_in[0];
    const int*   ei      = (const int*)d_in[1];
    const int*   batch   = (const int*)d_in[2];
    const float* fpts    = (const float*)d_in[3];
    const float* Wg      = (const float*)d_in[4];
    const float* att_src = (const float*)d_in[5];
    const float* att_dst = (const float*)d_in[6];
    const float* gat_b   = (const float*)d_in[7];
    const float* Wlg     = (const float*)d_in[8];
    const float* blg     = (const float*)d_in[9];
    const float* W1      = (const float*)d_in[10];
    const float* b1      = (const float*)d_in[11];
    const float* g1      = (const float*)d_in[12];
    const float* be1     = (const float*)d_in[13];
    const float* W2      = (const float*)d_in[14];
    const float* b2      = (const float*)d_in[15];
    const float* g2      = (const float*)d_in[16];
    const float* be2     = (const float*)d_in[17];
    const float* W3      = (const float*)d_in[18];
    const float* b3      = (const float*)d_in[19];
    const float* Wf      = (const float*)d_in[20];
    const float* bf      = (const float*)d_in[21];
    const float* gf      = (const float*)d_in[22];
    const float* bef     = (const float*)d_in[23];
    const float* Wl      = (const float*)d_in[24];
    const float* bl      = (const float*)d_in[25];
    float* out = (float*)d_out;

    size_t o = 0;
    auto alloc = [&](size_t nfloats) {
        float* p = (float*)((char*)d_ws + o);
        o += ((nfloats * sizeof(float) + 255) / 256) * 256;
        return p;
    };
    float* r1    = alloc(NN * 64);   // region R1: xl_bf during GAT; h1f/h2f/zb after
    float* r2    = alloc(NN * 64);   // region R2: CSR during GAT; bf16 arena after
    float* a_src = alloc(NN);
    float* a_dst = alloc(NN);
    float* gsum  = alloc(NG * 64);
    float* gcntf = alloc(NG);
    float* bnbuf = alloc(4096);      // sum | sumsq
    float* scale = alloc(1024);
    float* shift = alloc(1024);
    int* gcnt = (int*)gcntf;
    float* bnsum = bnbuf;
    float* bnsq  = bnbuf + 2048;

    // R1 aliases: xl_bf (6.4MB) dead after k_gather; then h1f/h2f/zb
    ushort_t* xl_bf = (ushort_t*)r1;   // [50000,64] bf16
    float* h1f = r1;                   // [1000,1024]
    float* h2f = r1 + 1048576;         // [1000,512]
    float* zb  = r1 + 1572864;         // [1000,512]

    // R2: CSR buffers during GAT (dead after k_gather), bf16 arena after
    int* csr_src = (int*)r2;                         // [800000] ints, bytes 0..3.2MB
    int* deg     = (int*)((char*)r2 + 3200000);      // [50000]
    int* rowptr  = (int*)((char*)r2 + 3400000);      // [50000]
    int* cursor  = (int*)((char*)r2 + 3600000);      // [50000]

    ushort_t* U = (ushort_t*)r2;       // capacity NN*64*2 = 6,400,000 halves
    ushort_t* cbuf_bf   = U + 0;        // [1000,512]
    ushort_t* pooled_bf = U + 524288;   // [1000,64]
    ushort_t* Wlg_bf    = U + 589824;   // [256,64]
    ushort_t* fpts_bf   = U + 655360;   // [1000,2048]  (dead after gemm1)
    ushort_t* W1_bf     = U + 2703360;  // [1024,2048]  (dead after gemm1)
    ushort_t* W2_bf     = U + 4800512;  // [512,1024]
    ushort_t* h1_bf     = U + 5324800;  // [1000,1024]
    ushort_t* h2_bf     = U + 655360;   // [1000,512]   (reuses fpts region)
    ushort_t* W3_bf     = U + 1200128;  // [256,512]
    ushort_t* Wf_bf     = U + 1331200;  // [512,512]

    // ---- GAT: projection + CSR build + fused gather/pool ----
    k_xl<<<NN / 4, 256, 0, stream>>>(x, Wg, att_src, att_dst, xl_bf, a_src, a_dst);
    hipMemsetAsync(deg, 0, NN * sizeof(int), stream);
    k_deg<<<(NE + 255) / 256, 256, 0, stream>>>(ei, deg);
    k_scan<<<1, 1024, 0, stream>>>(deg, rowptr, cursor);
    k_scatter<<<(NE + 255) / 256, 256, 0, stream>>>(ei, cursor, csr_src);
    hipMemsetAsync(gsum, 0, NG * 64 * sizeof(float), stream);
    hipMemsetAsync(gcnt, 0, NG * sizeof(int), stream);
    k_gather<<<NN / 4, 256, 0, stream>>>(csr_src, rowptr, deg, xl_bf, a_src, a_dst,
                                         gat_b, batch, gsum, gcnt);
    k_pooled<<<(NG * 64 + 255) / 256, 256, 0, stream>>>(gsum, gcnt, pooled_bf);

    // ---- conversions needed for gnn gemm + gemm1 + gemm2 ----
    k_f2b<<<(GOUTC * 64 + 2047) / 2048, 256, 0, stream>>>(Wlg, Wlg_bf, GOUTC * 64);
    k_f2b<<<(NG * FPC + 2047) / 2048, 256, 0, stream>>>(fpts, fpts_bf, NG * FPC);
    k_f2b<<<(H1C * FPC + 2047) / 2048, 256, 0, stream>>>(W1, W1_bf, H1C * FPC);
    k_f2b<<<(H2C * H1C + 2047) / 2048, 256, 0, stream>>>(W2, W2_bf, H2C * H1C);

    // gnn_out -> cbuf[:, 0:256] (bf16)
    k_mgemm<false, true><<<dim3(GOUTC / 64, 16), 256, 0, stream>>>(
        pooled_bf, Wlg_bf, blg, cbuf_bf, NG, GOUTC, 64, 512);

    // ---- MLP layer 1 ----
    k_mgemm<false, false><<<dim3(H1C / 64, 16), 256, 0, stream>>>(
        fpts_bf, W1_bf, b1, h1f, NG, H1C, FPC, H1C);
    hipMemsetAsync(bnbuf, 0, 4096 * sizeof(float), stream);
    k_bnpart<<<dim3(H1C / 256, 8), 256, 0, stream>>>(h1f, bnsum, bnsq, H1C);
    k_bnfin<<<(H1C + 255) / 256, 256, 0, stream>>>(bnsum, bnsq, g1, be1, scale, shift, H1C);
    k_bnrelu_bf<<<(NG * H1C / 4 + 255) / 256, 256, 0, stream>>>(
        h1f, scale, shift, h1_bf, H1C - 1, NG * H1C);

    // conversions for gemm3/gemmF (fpts/W1 region now dead)
    k_f2b<<<(MOUTC * H2C + 2047) / 2048, 256, 0, stream>>>(W3, W3_bf, MOUTC * H2C);
    k_f2b<<<(D1C * 512 + 2047) / 2048, 256, 0, stream>>>(Wf, Wf_bf, D1C * 512);

    // ---- MLP layer 2 ----
    k_mgemm<false, false><<<dim3(H2C / 64, 16), 256, 0, stream>>>(
        h1_bf, W2_bf, b2, h2f, NG, H2C, H1C, H2C);
    hipMemsetAsync(bnbuf, 0, 4096 * sizeof(float), stream);
    k_bnpart<<<dim3(H2C / 256, 8), 256, 0, stream>>>(h2f, bnsum, bnsq, H2C);
    k_bnfin<<<(H2C + 255) / 256, 256, 0, stream>>>(bnsum, bnsq, g2, be2, scale, shift, H2C);
    k_bnrelu_bf<<<(NG * H2C / 4 + 255) / 256, 256, 0, stream>>>(
        h2f, scale, shift, h2_bf, H2C - 1, NG * H2C);

    // mlp_out -> cbuf[:, 256:512] (bf16)
    k_mgemm<false, true><<<dim3(MOUTC / 64, 16), 256, 0, stream>>>(
        h2_bf, W3_bf, b3, cbuf_bf + 256, NG, MOUTC, H2C, 512);

    // ---- fusion head ----
    k_mgemm<true, false><<<dim3(D1C / 64, 16), 256, 0, stream>>>(
        cbuf_bf, Wf_bf, bf, zb, NG, D1C, GOUTC + MOUTC, D1C);
    hipMemsetAsync(bnbuf, 0, 4096 * sizeof(float), stream);
    k_bnpart<<<dim3(D1C / 256, 8), 256, 0, stream>>>(zb, bnsum, bnsq, D1C);
    k_bnfin<<<(D1C + 255) / 256, 256, 0, stream>>>(bnsum, bnsq, gf, bef, scale, shift, D1C);
    k_final<<<NG, 256, 0, stream>>>(zb, scale, shift, Wl, bl, out);
}

// Round 8
// 460.594 us; speedup vs baseline: 1.2452x; 1.2452x over previous
//
#include <hip/hip_runtime.h>

#define NN 50000
#define NE 800000
#define NG 1000
#define DIN 64
#define HIDC 64
#define GOUTC 256
#define FPC 2048
#define H1C 1024
#define H2C 512
#define MOUTC 256
#define D1C 512
#define EPSV 1e-5f
#define SLOPEV 0.2f
#define NB 196  // ceil(NN/256)

typedef __attribute__((ext_vector_type(8))) short s8v;
typedef __attribute__((ext_vector_type(4))) float f4v;
typedef unsigned short ushort_t;

__device__ inline ushort_t f2b(float f) {
    unsigned u = __builtin_bit_cast(unsigned, f);
    unsigned r = (u + 0x7FFFu + ((u >> 16) & 1u)) >> 16;
    return (ushort_t)r;
}
__device__ inline float b2f(ushort_t u) {
    return __builtin_bit_cast(float, ((unsigned)u) << 16);
}

// ---- GAT: xl_bf = bf16(x @ Wg^T) ; a_src = xl.att_src ; a_dst = xl.att_dst ----
__global__ void k_xl(const float* __restrict__ x, const float* __restrict__ Wg,
                     const float* __restrict__ att_src, const float* __restrict__ att_dst,
                     ushort_t* __restrict__ xl_bf, float* __restrict__ a_src,
                     float* __restrict__ a_dst) {
    __shared__ float Wgs[64][65];
    __shared__ float xs[4][64];
    int t = threadIdx.x;
    int lane = t & 63;
    int w = t >> 6;
    for (int i = t; i < 64 * 64; i += 256) Wgs[i >> 6][i & 63] = Wg[i];
    int node = blockIdx.x * 4 + w;
    xs[w][lane] = x[node * 64 + lane];
    __syncthreads();
    float acc = 0.f;
#pragma unroll
    for (int d = 0; d < 64; ++d) acc += xs[w][d] * Wgs[lane][d];
    xl_bf[node * 64 + lane] = f2b(acc);
    float vs = acc * att_src[lane];
    float vd = acc * att_dst[lane];
#pragma unroll
    for (int off = 32; off > 0; off >>= 1) {
        vs += __shfl_xor(vs, off);
        vd += __shfl_xor(vd, off);
    }
    if (lane == 0) { a_src[node] = vs; a_dst[node] = vd; }
}

// ---- CSR build: degree histogram ----
__global__ void k_deg(const int* __restrict__ ei, int* __restrict__ deg) {
    int e = blockIdx.x * 256 + threadIdx.x;
    if (e < NE) atomicAdd(&deg[ei[NE + e]], 1);
}

// ---- CSR build: hierarchical scan, stage 1: per-block sums ----
__global__ __launch_bounds__(256) void k_scan1(const int* __restrict__ deg,
                                               int* __restrict__ blocksum) {
    int b = blockIdx.x, t = threadIdx.x;
    int idx = b * 256 + t;
    int v = (idx < NN) ? deg[idx] : 0;
#pragma unroll
    for (int off = 32; off > 0; off >>= 1) v += __shfl_xor(v, off);
    __shared__ int ws[4];
    if ((t & 63) == 0) ws[t >> 6] = v;
    __syncthreads();
    if (t == 0) blocksum[b] = ws[0] + ws[1] + ws[2] + ws[3];
}

// ---- CSR build: stage 2: block base + local 256-wide scan -> rowptr/cursor ----
__global__ __launch_bounds__(256) void k_scan2(const int* __restrict__ deg,
                                               const int* __restrict__ blocksum,
                                               int* __restrict__ rowptr,
                                               int* __restrict__ cursor) {
    int b = blockIdx.x, t = threadIdx.x;
    int v = (t < b) ? blocksum[t] : 0;  // NB=196 < 256: one value per thread
#pragma unroll
    for (int off = 32; off > 0; off >>= 1) v += __shfl_xor(v, off);
    __shared__ int ws[4];
    __shared__ int sc[256];
    if ((t & 63) == 0) ws[t >> 6] = v;
    int idx = b * 256 + t;
    int d = (idx < NN) ? deg[idx] : 0;
    sc[t] = d;
    __syncthreads();
    int base = ws[0] + ws[1] + ws[2] + ws[3];
    for (int off = 1; off < 256; off <<= 1) {
        int x = (t >= off) ? sc[t - off] : 0;
        __syncthreads();
        sc[t] += x;
        __syncthreads();
    }
    if (idx < NN) {
        int ex = base + sc[t] - d;  // exclusive prefix
        rowptr[idx] = ex;
        cursor[idx] = ex;
    }
}

// ---- CSR build: scatter src indices by dst ----
__global__ void k_scatter(const int* __restrict__ ei, int* __restrict__ cursor,
                          int* __restrict__ csr_src) {
    int e = blockIdx.x * 256 + threadIdx.x;
    if (e < NE) {
        int d = ei[NE + e];
        int pos = atomicAdd(&cursor[d], 1);
        csr_src[pos] = ei[e];
    }
}

// ---- fused gather: softmax-weighted aggregation + bias + relu + mean-pool ----
__global__ void k_gather(const int* __restrict__ csr_src, const int* __restrict__ rowptr,
                         const int* __restrict__ deg, const ushort_t* __restrict__ xl_bf,
                         const float* __restrict__ a_src, const float* __restrict__ a_dst,
                         const float* __restrict__ gat_bias, const int* __restrict__ batch,
                         float* __restrict__ gsum, int* __restrict__ gcnt) {
    int t = threadIdx.x, lane = t & 63, w = t >> 6;
    int n = blockIdx.x * 4 + w;
    float ad = a_dst[n];
    float ev = a_src[n] + ad;
    ev = ev > 0.f ? ev : SLOPEV * ev;
    float ex = expf(ev);
    float den = ex;
    float acc = ex * b2f(xl_bf[(size_t)n * 64 + lane]);
    int beg = rowptr[n];
    int end = beg + deg[n];
    int j = beg;
    for (; j + 4 <= end; j += 4) {
        int s0 = csr_src[j], s1 = csr_src[j + 1], s2 = csr_src[j + 2], s3 = csr_src[j + 3];
        float e0 = a_src[s0] + ad, e1 = a_src[s1] + ad, e2 = a_src[s2] + ad, e3 = a_src[s3] + ad;
        e0 = e0 > 0.f ? e0 : SLOPEV * e0;
        e1 = e1 > 0.f ? e1 : SLOPEV * e1;
        e2 = e2 > 0.f ? e2 : SLOPEV * e2;
        e3 = e3 > 0.f ? e3 : SLOPEV * e3;
        float x0 = expf(e0), x1 = expf(e1), x2 = expf(e2), x3 = expf(e3);
        float v0 = b2f(xl_bf[(size_t)s0 * 64 + lane]);
        float v1 = b2f(xl_bf[(size_t)s1 * 64 + lane]);
        float v2 = b2f(xl_bf[(size_t)s2 * 64 + lane]);
        float v3 = b2f(xl_bf[(size_t)s3 * 64 + lane]);
        den += x0 + x1 + x2 + x3;
        acc += x0 * v0;
        acc += x1 * v1;
        acc += x2 * v2;
        acc += x3 * v3;
    }
    for (; j < end; ++j) {
        int s0 = csr_src[j];
        float e0 = a_src[s0] + ad;
        e0 = e0 > 0.f ? e0 : SLOPEV * e0;
        float x0 = expf(e0);
        den += x0;
        acc += x0 * b2f(xl_bf[(size_t)s0 * 64 + lane]);
    }
    float v = acc / den + gat_bias[lane];
    v = v > 0.f ? v : 0.f;
    int b = batch[n];
    atomicAdd(&gsum[b * 64 + lane], v);
    if (lane == 0) atomicAdd(&gcnt[b], 1);
}

__global__ void k_pooled(const float* __restrict__ gsum, const int* __restrict__ gcnt,
                         ushort_t* __restrict__ pooled_bf) {
    int i = blockIdx.x * 256 + threadIdx.x;
    if (i < NG * 64) {
        float c = (float)gcnt[i >> 6];
        pooled_bf[i] = f2b(gsum[i] / fmaxf(c, 1.f));
    }
}

// ---- fp32 -> bf16 conversion (8 elems/thread) ----
__global__ void k_f2b(const float* __restrict__ s, ushort_t* __restrict__ d, int n) {
    int i = (blockIdx.x * 256 + threadIdx.x) * 8;
    if (i + 8 <= n) {
#pragma unroll
        for (int j = 0; j < 8; ++j) d[i + j] = f2b(s[i + j]);
    } else {
        for (int j = i; j < n; ++j) d[j] = f2b(s[j]);
    }
}

// ---- bf16 MFMA GEMM: C[M,N](ldc) = A[M,K]bf16 @ B[N,K]bf16^T + bias ----
template <bool RELU, bool OBF16>
__global__ __launch_bounds__(256) void k_mgemm(const ushort_t* __restrict__ A,
                                               const ushort_t* __restrict__ B,
                                               const float* __restrict__ bias, void* Cv,
                                               int M, int N, int K, int ldc) {
    __shared__ ushort_t As[64][40];
    __shared__ ushort_t Bs[64][40];
    int t = threadIdx.x;
    int lane = t & 63, w = t >> 6;
    int wr = w >> 1, wc = w & 1;
    int bm = blockIdx.y * 64, bn = blockIdx.x * 64;
    f4v acc[2][2];
#pragma unroll
    for (int m = 0; m < 2; ++m)
#pragma unroll
        for (int n = 0; n < 2; ++n) acc[m][n] = (f4v){0.f, 0.f, 0.f, 0.f};

    int lr = t >> 2;
    int lk = (t & 3) * 8;
    int arow = bm + lr;
    bool aval = arow < M;
    const ushort_t* aptr = A + (size_t)(aval ? arow : (M - 1)) * K + lk;
    const ushort_t* bptr = B + (size_t)(bn + lr) * K + lk;
    int fr = lane & 15, kg = lane >> 4;

    for (int k0 = 0; k0 < K; k0 += 32) {
        s8v av = {};
        if (aval) av = *(const s8v*)(aptr + k0);
        s8v bv = *(const s8v*)(bptr + k0);
        *(s8v*)&As[lr][lk] = av;
        *(s8v*)&Bs[lr][lk] = bv;
        __syncthreads();
        s8v bfrag0 = *(const s8v*)&Bs[wc * 32 + 0 * 16 + fr][kg * 8];
        s8v bfrag1 = *(const s8v*)&Bs[wc * 32 + 1 * 16 + fr][kg * 8];
#pragma unroll
        for (int m = 0; m < 2; ++m) {
            s8v af = *(const s8v*)&As[wr * 32 + m * 16 + fr][kg * 8];
            acc[m][0] = __builtin_amdgcn_mfma_f32_16x16x32_bf16(af, bfrag0, acc[m][0], 0, 0, 0);
            acc[m][1] = __builtin_amdgcn_mfma_f32_16x16x32_bf16(af, bfrag1, acc[m][1], 0, 0, 0);
        }
        __syncthreads();
    }
    int fq = lane >> 4;
#pragma unroll
    for (int m = 0; m < 2; ++m) {
        int row = bm + wr * 32 + m * 16 + fq * 4;
#pragma unroll
        for (int n = 0; n < 2; ++n) {
            int col = bn + wc * 32 + n * 16 + fr;
            float bb = bias[col];
#pragma unroll
            for (int r = 0; r < 4; ++r) {
                int gr = row + r;
                if (gr < M) {
                    float v = acc[m][n][r] + bb;
                    if (RELU) v = fmaxf(v, 0.f);
                    if (OBF16) ((ushort_t*)Cv)[(size_t)gr * ldc + col] = f2b(v);
                    else ((float*)Cv)[(size_t)gr * ldc + col] = v;
                }
            }
        }
    }
}

// ---- BN: row-split partial sums -> finalize -> normalize(+relu)+bf16 ----
__global__ void k_bnpart(const float* __restrict__ h, float* __restrict__ sum,
                         float* __restrict__ sumsq, int ncols) {
    int col = blockIdx.x * 256 + threadIdx.x;
    int r0 = blockIdx.y * 125;
    float s = 0.f, q = 0.f;
    for (int r = r0; r < r0 + 125; ++r) {
        float v = h[(size_t)r * ncols + col];
        s += v;
        q += v * v;
    }
    atomicAdd(&sum[col], s);
    atomicAdd(&sumsq[col], q);
}

__global__ void k_bnfin(const float* __restrict__ sum, const float* __restrict__ sumsq,
                        const float* __restrict__ gamma, const float* __restrict__ beta,
                        float* __restrict__ scale, float* __restrict__ shift, int ncols) {
    int col = blockIdx.x * 256 + threadIdx.x;
    if (col >= ncols) return;
    float mu = sum[col] * (1.f / NG);
    float var = sumsq[col] * (1.f / NG) - mu * mu;
    float rstd = rsqrtf(var + EPSV);
    float sc = gamma[col] * rstd;
    scale[col] = sc;
    shift[col] = beta[col] - mu * sc;
}

__global__ void k_bnrelu_bf(const float* __restrict__ h, const float* __restrict__ scale,
                            const float* __restrict__ shift, ushort_t* __restrict__ dst,
                            int colmask, int total) {
    int i = (blockIdx.x * 256 + threadIdx.x) * 4;
    if (i < total) {
#pragma unroll
        for (int j = 0; j < 4; ++j) {
            int col = (i + j) & colmask;
            float v = h[i + j] * scale[col] + shift[col];
            dst[i + j] = f2b(fmaxf(v, 0.f));
        }
    }
}

// ---- final: out[g] = sum_j (z[g,j]*scale[j]+shift[j]) * Wl[j] + bl ----
__global__ void k_final(const float* __restrict__ z, const float* __restrict__ scale,
                        const float* __restrict__ shift, const float* __restrict__ Wl,
                        const float* __restrict__ bl, float* __restrict__ out) {
    int g = blockIdx.x;
    int t = threadIdx.x;
    float acc = 0.f;
    for (int j = t; j < D1C; j += 256) {
        float v = z[g * D1C + j] * scale[j] + shift[j];
        acc += v * Wl[j];
    }
#pragma unroll
    for (int off = 32; off > 0; off >>= 1) acc += __shfl_xor(acc, off);
    __shared__ float red[4];
    int lane = t & 63, w = t >> 6;
    if (lane == 0) red[w] = acc;
    __syncthreads();
    if (t == 0) out[g] = red[0] + red[1] + red[2] + red[3] + bl[0];
}

extern "C" void kernel_launch(void* const* d_in, const int* in_sizes, int n_in,
                              void* d_out, int out_size, void* d_ws, size_t ws_size,
                              hipStream_t stream) {
    const float* x       = (const float*)d_in[0];
    const int*   ei      = (const int*)d_in[1];
    const int*   batch   = (const int*)d_in[2];
    const float* fpts    = (const float*)d_in[3];
    const float* Wg      = (const float*)d_in[4];
    const float* att_src = (const float*)d_in[5];
    const float* att_dst = (const float*)d_in[6];
    const float* gat_b   = (const float*)d_in[7];
    const float* Wlg     = (const float*)d_in[8];
    const float* blg     = (const float*)d_in[9];
    const float* W1      = (const float*)d_in[10];
    const float* b1      = (const float*)d_in[11];
    const float* g1      = (const float*)d_in[12];
    const float* be1     = (const float*)d_in[13];
    const float* W2      = (const float*)d_in[14];
    const float* b2      = (const float*)d_in[15];
    const float* g2      = (const float*)d_in[16];
    const float* be2     = (const float*)d_in[17];
    const float* W3      = (const float*)d_in[18];
    const float* b3      = (const float*)d_in[19];
    const float* Wf      = (const float*)d_in[20];
    const float* bf      = (const float*)d_in[21];
    const float* gf      = (const float*)d_in[22];
    const float* bef     = (const float*)d_in[23];
    const float* Wl      = (const float*)d_in[24];
    const float* bl      = (const float*)d_in[25];
    float* out = (float*)d_out;

    size_t o = 0;
    auto alloc = [&](size_t nfloats) {
        float* p = (float*)((char*)d_ws + o);
        o += ((nfloats * sizeof(float) + 255) / 256) * 256;
        return p;
    };
    float* r1    = alloc(NN * 64);   // region R1: xl_bf during GAT; h1f/h2f/zb after
    float* r2    = alloc(NN * 64);   // region R2: CSR during GAT; bf16 arena after
    float* a_src = alloc(NN);
    float* a_dst = alloc(NN);
    float* gsum  = alloc(NG * 64);
    float* gcntf = alloc(NG);
    float* bnbuf = alloc(4096);      // sum | sumsq
    float* scale = alloc(1024);
    float* shift = alloc(1024);
    int* gcnt = (int*)gcntf;
    float* bnsum = bnbuf;
    float* bnsq  = bnbuf + 2048;

    // R1 aliases: xl_bf (6.4MB) dead after k_gather; then h1f/h2f/zb
    ushort_t* xl_bf = (ushort_t*)r1;   // [50000,64] bf16
    float* h1f = r1;                   // [1000,1024]
    float* h2f = r1 + 1048576;         // [1000,512]
    float* zb  = r1 + 1572864;         // [1000,512]

    // R2: CSR buffers during GAT (dead after k_gather), bf16 arena after
    int* csr_src = (int*)r2;                         // [800000] ints, bytes 0..3.2MB
    int* deg     = (int*)((char*)r2 + 3200000);      // [50000]
    int* rowptr  = (int*)((char*)r2 + 3400000);      // [50000]
    int* cursor  = (int*)((char*)r2 + 3600000);      // [50000]
    int* blocksum= (int*)((char*)r2 + 3800000);      // [196]

    ushort_t* U = (ushort_t*)r2;       // capacity NN*64*2 = 6,400,000 halves
    ushort_t* cbuf_bf   = U + 0;        // [1000,512]
    ushort_t* pooled_bf = U + 524288;   // [1000,64]
    ushort_t* Wlg_bf    = U + 589824;   // [256,64]
    ushort_t* fpts_bf   = U + 655360;   // [1000,2048]  (dead after gemm1)
    ushort_t* W1_bf     = U + 2703360;  // [1024,2048]  (dead after gemm1)
    ushort_t* W2_bf     = U + 4800512;  // [512,1024]
    ushort_t* h1_bf     = U + 5324800;  // [1000,1024]
    ushort_t* h2_bf     = U + 655360;   // [1000,512]   (reuses fpts region)
    ushort_t* W3_bf     = U + 1200128;  // [256,512]
    ushort_t* Wf_bf     = U + 1331200;  // [512,512]

    // ---- GAT: projection + CSR build + fused gather/pool ----
    k_xl<<<NN / 4, 256, 0, stream>>>(x, Wg, att_src, att_dst, xl_bf, a_src, a_dst);
    hipMemsetAsync(deg, 0, NN * sizeof(int), stream);
    k_deg<<<(NE + 255) / 256, 256, 0, stream>>>(ei, deg);
    k_scan1<<<NB, 256, 0, stream>>>(deg, blocksum);
    k_scan2<<<NB, 256, 0, stream>>>(deg, blocksum, rowptr, cursor);
    k_scatter<<<(NE + 255) / 256, 256, 0, stream>>>(ei, cursor, csr_src);
    hipMemsetAsync(gsum, 0, NG * 64 * sizeof(float), stream);
    hipMemsetAsync(gcnt, 0, NG * sizeof(int), stream);
    k_gather<<<NN / 4, 256, 0, stream>>>(csr_src, rowptr, deg, xl_bf, a_src, a_dst,
                                         gat_b, batch, gsum, gcnt);
    k_pooled<<<(NG * 64 + 255) / 256, 256, 0, stream>>>(gsum, gcnt, pooled_bf);

    // ---- conversions needed for gnn gemm + gemm1 + gemm2 ----
    k_f2b<<<(GOUTC * 64 + 2047) / 2048, 256, 0, stream>>>(Wlg, Wlg_bf, GOUTC * 64);
    k_f2b<<<(NG * FPC + 2047) / 2048, 256, 0, stream>>>(fpts, fpts_bf, NG * FPC);
    k_f2b<<<(H1C * FPC + 2047) / 2048, 256, 0, stream>>>(W1, W1_bf, H1C * FPC);
    k_f2b<<<(H2C * H1C + 2047) / 2048, 256, 0, stream>>>(W2, W2_bf, H2C * H1C);

    // gnn_out -> cbuf[:, 0:256] (bf16)
    k_mgemm<false, true><<<dim3(GOUTC / 64, 16), 256, 0, stream>>>(
        pooled_bf, Wlg_bf, blg, cbuf_bf, NG, GOUTC, 64, 512);

    // ---- MLP layer 1 ----
    k_mgemm<false, false><<<dim3(H1C / 64, 16), 256, 0, stream>>>(
        fpts_bf, W1_bf, b1, h1f, NG, H1C, FPC, H1C);
    hipMemsetAsync(bnbuf, 0, 4096 * sizeof(float), stream);
    k_bnpart<<<dim3(H1C / 256, 8), 256, 0, stream>>>(h1f, bnsum, bnsq, H1C);
    k_bnfin<<<(H1C + 255) / 256, 256, 0, stream>>>(bnsum, bnsq, g1, be1, scale, shift, H1C);
    k_bnrelu_bf<<<(NG * H1C / 4 + 255) / 256, 256, 0, stream>>>(
        h1f, scale, shift, h1_bf, H1C - 1, NG * H1C);

    // conversions for gemm3/gemmF (fpts/W1 region now dead)
    k_f2b<<<(MOUTC * H2C + 2047) / 2048, 256, 0, stream>>>(W3, W3_bf, MOUTC * H2C);
    k_f2b<<<(D1C * 512 + 2047) / 2048, 256, 0, stream>>>(Wf, Wf_bf, D1C * 512);

    // ---- MLP layer 2 ----
    k_mgemm<false, false><<<dim3(H2C / 64, 16), 256, 0, stream>>>(
        h1_bf, W2_bf, b2, h2f, NG, H2C, H1C, H2C);
    hipMemsetAsync(bnbuf, 0, 4096 * sizeof(float), stream);
    k_bnpart<<<dim3(H2C / 256, 8), 256, 0, stream>>>(h2f, bnsum, bnsq, H2C);
    k_bnfin<<<(H2C + 255) / 256, 256, 0, stream>>>(bnsum, bnsq, g2, be2, scale, shift, H2C);
    k_bnrelu_bf<<<(NG * H2C / 4 + 255) / 256, 256, 0, stream>>>(
        h2f, scale, shift, h2_bf, H2C - 1, NG * H2C);

    // mlp_out -> cbuf[:, 256:512] (bf16)
    k_mgemm<false, true><<<dim3(MOUTC / 64, 16), 256, 0, stream>>>(
        h2_bf, W3_bf, b3, cbuf_bf + 256, NG, MOUTC, H2C, 512);

    // ---- fusion head ----
    k_mgemm<true, false><<<dim3(D1C / 64, 16), 256, 0, stream>>>(
        cbuf_bf, Wf_bf, bf, zb, NG, D1C, GOUTC + MOUTC, D1C);
    hipMemsetAsync(bnbuf, 0, 4096 * sizeof(float), stream);
    k_bnpart<<<dim3(D1C / 256, 8), 256, 0, stream>>>(zb, bnsum, bnsq, D1C);
    k_bnfin<<<(D1C + 255) / 256, 256, 0, stream>>>(bnsum, bnsq, gf, bef, scale, shift, D1C);
    k_final<<<NG, 256, 0, stream>>>(zb, scale, shift, Wl, bl, out);
}

// Round 9
// 453.942 us; speedup vs baseline: 1.2635x; 1.0147x over previous
//
#include <hip/hip_runtime.h>

#define NN 50000
#define NE 800000
#define NG 1000
#define DIN 64
#define HIDC 64
#define GOUTC 256
#define FPC 2048
#define H1C 1024
#define H2C 512
#define MOUTC 256
#define D1C 512
#define EPSV 1e-5f
#define SLOPEV 0.2f
#define NB 196  // ceil(NN/256)

typedef __attribute__((ext_vector_type(8))) short s8v;
typedef __attribute__((ext_vector_type(4))) float f4v;
typedef unsigned short ushort_t;

__device__ inline ushort_t f2b(float f) {
    unsigned u = __builtin_bit_cast(unsigned, f);
    unsigned r = (u + 0x7FFFu + ((u >> 16) & 1u)) >> 16;
    return (ushort_t)r;
}
__device__ inline float b2f(ushort_t u) {
    return __builtin_bit_cast(float, ((unsigned)u) << 16);
}

// ---- GAT: xl_bf = bf16(x @ Wg^T) ; a_src = xl.att_src ; a_dst = xl.att_dst ----
__global__ void k_xl(const float* __restrict__ x, const float* __restrict__ Wg,
                     const float* __restrict__ att_src, const float* __restrict__ att_dst,
                     ushort_t* __restrict__ xl_bf, float* __restrict__ a_src,
                     float* __restrict__ a_dst) {
    __shared__ float Wgs[64][65];
    __shared__ float xs[4][64];
    int t = threadIdx.x;
    int lane = t & 63;
    int w = t >> 6;
    for (int i = t; i < 64 * 64; i += 256) Wgs[i >> 6][i & 63] = Wg[i];
    int node = blockIdx.x * 4 + w;
    xs[w][lane] = x[node * 64 + lane];
    __syncthreads();
    float acc = 0.f;
#pragma unroll
    for (int d = 0; d < 64; ++d) acc += xs[w][d] * Wgs[lane][d];
    xl_bf[node * 64 + lane] = f2b(acc);
    float vs = acc * att_src[lane];
    float vd = acc * att_dst[lane];
#pragma unroll
    for (int off = 32; off > 0; off >>= 1) {
        vs += __shfl_xor(vs, off);
        vd += __shfl_xor(vd, off);
    }
    if (lane == 0) { a_src[node] = vs; a_dst[node] = vd; }
}

// ---- CSR build: degree histogram ----
__global__ void k_deg(const int* __restrict__ ei, int* __restrict__ deg) {
    int e = blockIdx.x * 256 + threadIdx.x;
    if (e < NE) atomicAdd(&deg[ei[NE + e]], 1);
}

// ---- CSR build: hierarchical scan, stage 1: per-block sums ----
__global__ __launch_bounds__(256) void k_scan1(const int* __restrict__ deg,
                                               int* __restrict__ blocksum) {
    int b = blockIdx.x, t = threadIdx.x;
    int idx = b * 256 + t;
    int v = (idx < NN) ? deg[idx] : 0;
#pragma unroll
    for (int off = 32; off > 0; off >>= 1) v += __shfl_xor(v, off);
    __shared__ int ws[4];
    if ((t & 63) == 0) ws[t >> 6] = v;
    __syncthreads();
    if (t == 0) blocksum[b] = ws[0] + ws[1] + ws[2] + ws[3];
}

// ---- CSR build: stage 2: block base + local 256-wide scan -> rowptr/cursor ----
__global__ __launch_bounds__(256) void k_scan2(const int* __restrict__ deg,
                                               const int* __restrict__ blocksum,
                                               int* __restrict__ rowptr,
                                               int* __restrict__ cursor) {
    int b = blockIdx.x, t = threadIdx.x;
    int v = (t < b) ? blocksum[t] : 0;  // NB=196 < 256: one value per thread
#pragma unroll
    for (int off = 32; off > 0; off >>= 1) v += __shfl_xor(v, off);
    __shared__ int ws[4];
    __shared__ int sc[256];
    if ((t & 63) == 0) ws[t >> 6] = v;
    int idx = b * 256 + t;
    int d = (idx < NN) ? deg[idx] : 0;
    sc[t] = d;
    __syncthreads();
    int base = ws[0] + ws[1] + ws[2] + ws[3];
    for (int off = 1; off < 256; off <<= 1) {
        int x = (t >= off) ? sc[t - off] : 0;
        __syncthreads();
        sc[t] += x;
        __syncthreads();
    }
    if (idx < NN) {
        int ex = base + sc[t] - d;  // exclusive prefix
        rowptr[idx] = ex;
        cursor[idx] = ex;
    }
}

// ---- CSR build: scatter src indices + precomputed softmax weights ----
__global__ void k_scatter(const int* __restrict__ ei, const float* __restrict__ a_src,
                          const float* __restrict__ a_dst, int* __restrict__ cursor,
                          int* __restrict__ csr_src, float* __restrict__ csr_w) {
    int e = blockIdx.x * 256 + threadIdx.x;
    if (e < NE) {
        int s = ei[e];
        int d = ei[NE + e];
        int pos = atomicAdd(&cursor[d], 1);
        float ev = a_src[s] + a_dst[d];
        ev = ev > 0.f ? ev : SLOPEV * ev;
        csr_src[pos] = s;
        csr_w[pos] = expf(ev);
    }
}

// ---- fused gather: weighted aggregation + bias + relu + mean-pool ----
__global__ void k_gather(const int* __restrict__ csr_src, const float* __restrict__ csr_w,
                         const int* __restrict__ rowptr, const int* __restrict__ deg,
                         const ushort_t* __restrict__ xl_bf,
                         const float* __restrict__ a_src, const float* __restrict__ a_dst,
                         const float* __restrict__ gat_bias, const int* __restrict__ batch,
                         float* __restrict__ gsum, int* __restrict__ gcnt) {
    int t = threadIdx.x, lane = t & 63, w = t >> 6;
    int n = blockIdx.x * 4 + w;
    // self loop
    float ev = a_src[n] + a_dst[n];
    ev = ev > 0.f ? ev : SLOPEV * ev;
    float ex = expf(ev);
    float den = ex;
    float acc = ex * b2f(xl_bf[(size_t)n * 64 + lane]);
    int beg = rowptr[n];
    int end = beg + deg[n];
    int j = beg;
    for (; j + 4 <= end; j += 4) {
        int s0 = csr_src[j], s1 = csr_src[j + 1], s2 = csr_src[j + 2], s3 = csr_src[j + 3];
        float x0 = csr_w[j], x1 = csr_w[j + 1], x2 = csr_w[j + 2], x3 = csr_w[j + 3];
        float v0 = b2f(xl_bf[(size_t)s0 * 64 + lane]);
        float v1 = b2f(xl_bf[(size_t)s1 * 64 + lane]);
        float v2 = b2f(xl_bf[(size_t)s2 * 64 + lane]);
        float v3 = b2f(xl_bf[(size_t)s3 * 64 + lane]);
        den += x0 + x1 + x2 + x3;
        acc += x0 * v0;
        acc += x1 * v1;
        acc += x2 * v2;
        acc += x3 * v3;
    }
    for (; j < end; ++j) {
        int s0 = csr_src[j];
        float x0 = csr_w[j];
        den += x0;
        acc += x0 * b2f(xl_bf[(size_t)s0 * 64 + lane]);
    }
    float v = acc / den + gat_bias[lane];
    v = v > 0.f ? v : 0.f;
    int b = batch[n];
    atomicAdd(&gsum[b * 64 + lane], v);
    if (lane == 0) atomicAdd(&gcnt[b], 1);
}

__global__ void k_pooled(const float* __restrict__ gsum, const int* __restrict__ gcnt,
                         ushort_t* __restrict__ pooled_bf) {
    int i = blockIdx.x * 256 + threadIdx.x;
    if (i < NG * 64) {
        float c = (float)gcnt[i >> 6];
        pooled_bf[i] = f2b(gsum[i] / fmaxf(c, 1.f));
    }
}

// ---- fp32 -> bf16 conversion (8 elems/thread) ----
__global__ void k_f2b(const float* __restrict__ s, ushort_t* __restrict__ d, int n) {
    int i = (blockIdx.x * 256 + threadIdx.x) * 8;
    if (i + 8 <= n) {
#pragma unroll
        for (int j = 0; j < 8; ++j) d[i + j] = f2b(s[i + j]);
    } else {
        for (int j = i; j < n; ++j) d[j] = f2b(s[j]);
    }
}

// ---- bf16 MFMA GEMM: C[M,N](ldc) = A[M,K]bf16 @ B[N,K]bf16^T + bias ----
template <bool RELU, bool OBF16>
__global__ __launch_bounds__(256) void k_mgemm(const ushort_t* __restrict__ A,
                                               const ushort_t* __restrict__ B,
                                               const float* __restrict__ bias, void* Cv,
                                               int M, int N, int K, int ldc) {
    __shared__ ushort_t As[64][40];
    __shared__ ushort_t Bs[64][40];
    int t = threadIdx.x;
    int lane = t & 63, w = t >> 6;
    int wr = w >> 1, wc = w & 1;
    int bm = blockIdx.y * 64, bn = blockIdx.x * 64;
    f4v acc[2][2];
#pragma unroll
    for (int m = 0; m < 2; ++m)
#pragma unroll
        for (int n = 0; n < 2; ++n) acc[m][n] = (f4v){0.f, 0.f, 0.f, 0.f};

    int lr = t >> 2;
    int lk = (t & 3) * 8;
    int arow = bm + lr;
    bool aval = arow < M;
    const ushort_t* aptr = A + (size_t)(aval ? arow : (M - 1)) * K + lk;
    const ushort_t* bptr = B + (size_t)(bn + lr) * K + lk;
    int fr = lane & 15, kg = lane >> 4;

    for (int k0 = 0; k0 < K; k0 += 32) {
        s8v av = {};
        if (aval) av = *(const s8v*)(aptr + k0);
        s8v bv = *(const s8v*)(bptr + k0);
        *(s8v*)&As[lr][lk] = av;
        *(s8v*)&Bs[lr][lk] = bv;
        __syncthreads();
        s8v bfrag0 = *(const s8v*)&Bs[wc * 32 + 0 * 16 + fr][kg * 8];
        s8v bfrag1 = *(const s8v*)&Bs[wc * 32 + 1 * 16 + fr][kg * 8];
#pragma unroll
        for (int m = 0; m < 2; ++m) {
            s8v af = *(const s8v*)&As[wr * 32 + m * 16 + fr][kg * 8];
            acc[m][0] = __builtin_amdgcn_mfma_f32_16x16x32_bf16(af, bfrag0, acc[m][0], 0, 0, 0);
            acc[m][1] = __builtin_amdgcn_mfma_f32_16x16x32_bf16(af, bfrag1, acc[m][1], 0, 0, 0);
        }
        __syncthreads();
    }
    int fq = lane >> 4;
#pragma unroll
    for (int m = 0; m < 2; ++m) {
        int row = bm + wr * 32 + m * 16 + fq * 4;
#pragma unroll
        for (int n = 0; n < 2; ++n) {
            int col = bn + wc * 32 + n * 16 + fr;
            float bb = bias[col];
#pragma unroll
            for (int r = 0; r < 4; ++r) {
                int gr = row + r;
                if (gr < M) {
                    float v = acc[m][n][r] + bb;
                    if (RELU) v = fmaxf(v, 0.f);
                    if (OBF16) ((ushort_t*)Cv)[(size_t)gr * ldc + col] = f2b(v);
                    else ((float*)Cv)[(size_t)gr * ldc + col] = v;
                }
            }
        }
    }
}

// ---- BN: row-split partial sums -> finalize -> normalize(+relu)+bf16 ----
__global__ void k_bnpart(const float* __restrict__ h, float* __restrict__ sum,
                         float* __restrict__ sumsq, int ncols) {
    int col = blockIdx.x * 256 + threadIdx.x;
    int r0 = blockIdx.y * 125;
    float s = 0.f, q = 0.f;
    for (int r = r0; r < r0 + 125; ++r) {
        float v = h[(size_t)r * ncols + col];
        s += v;
        q += v * v;
    }
    atomicAdd(&sum[col], s);
    atomicAdd(&sumsq[col], q);
}

__global__ void k_bnfin(const float* __restrict__ sum, const float* __restrict__ sumsq,
                        const float* __restrict__ gamma, const float* __restrict__ beta,
                        float* __restrict__ scale, float* __restrict__ shift, int ncols) {
    int col = blockIdx.x * 256 + threadIdx.x;
    if (col >= ncols) return;
    float mu = sum[col] * (1.f / NG);
    float var = sumsq[col] * (1.f / NG) - mu * mu;
    float rstd = rsqrtf(var + EPSV);
    float sc = gamma[col] * rstd;
    scale[col] = sc;
    shift[col] = beta[col] - mu * sc;
}

__global__ void k_bnrelu_bf(const float* __restrict__ h, const float* __restrict__ scale,
                            const float* __restrict__ shift, ushort_t* __restrict__ dst,
                            int colmask, int total) {
    int i = (blockIdx.x * 256 + threadIdx.x) * 4;
    if (i < total) {
#pragma unroll
        for (int j = 0; j < 4; ++j) {
            int col = (i + j) & colmask;
            float v = h[i + j] * scale[col] + shift[col];
            dst[i + j] = f2b(fmaxf(v, 0.f));
        }
    }
}

// ---- final: out[g] = sum_j (z[g,j]*scale[j]+shift[j]) * Wl[j] + bl ----
__global__ void k_final(const float* __restrict__ z, const float* __restrict__ scale,
                        const float* __restrict__ shift, const float* __restrict__ Wl,
                        const float* __restrict__ bl, float* __restrict__ out) {
    int g = blockIdx.x;
    int t = threadIdx.x;
    float acc = 0.f;
    for (int j = t; j < D1C; j += 256) {
        float v = z[g * D1C + j] * scale[j] + shift[j];
        acc += v * Wl[j];
    }
#pragma unroll
    for (int off = 32; off > 0; off >>= 1) acc += __shfl_xor(acc, off);
    __shared__ float red[4];
    int lane = t & 63, w = t >> 6;
    if (lane == 0) red[w] = acc;
    __syncthreads();
    if (t == 0) out[g] = red[0] + red[1] + red[2] + red[3] + bl[0];
}

extern "C" void kernel_launch(void* const* d_in, const int* in_sizes, int n_in,
                              void* d_out, int out_size, void* d_ws, size_t ws_size,
                              hipStream_t stream) {
    const float* x       = (const float*)d_in[0];
    const int*   ei      = (const int*)d_in[1];
    const int*   batch   = (const int*)d_in[2];
    const float* fpts    = (const float*)d_in[3];
    const float* Wg      = (const float*)d_in[4];
    const float* att_src = (const float*)d_in[5];
    const float* att_dst = (const float*)d_in[6];
    const float* gat_b   = (const float*)d_in[7];
    const float* Wlg     = (const float*)d_in[8];
    const float* blg     = (const float*)d_in[9];
    const float* W1      = (const float*)d_in[10];
    const float* b1      = (const float*)d_in[11];
    const float* g1      = (const float*)d_in[12];
    const float* be1     = (const float*)d_in[13];
    const float* W2      = (const float*)d_in[14];
    const float* b2      = (const float*)d_in[15];
    const float* g2      = (const float*)d_in[16];
    const float* be2     = (const float*)d_in[17];
    const float* W3      = (const float*)d_in[18];
    const float* b3      = (const float*)d_in[19];
    const float* Wf      = (const float*)d_in[20];
    const float* bf      = (const float*)d_in[21];
    const float* gf      = (const float*)d_in[22];
    const float* bef     = (const float*)d_in[23];
    const float* Wl      = (const float*)d_in[24];
    const float* bl      = (const float*)d_in[25];
    float* out = (float*)d_out;

    size_t o = 0;
    auto alloc = [&](size_t nfloats) {
        float* p = (float*)((char*)d_ws + o);
        o += ((nfloats * sizeof(float) + 255) / 256) * 256;
        return p;
    };
    float* r1    = alloc(NN * 64);   // region R1: xl_bf during GAT; h1f/h2f/zb after
    float* r2    = alloc(NN * 64);   // region R2: CSR during GAT; bf16 arena after
    float* a_src = alloc(NN);
    float* a_dst = alloc(NN);
    float* gsum  = alloc(NG * 64);
    float* gcntf = alloc(NG);
    float* bnbuf = alloc(4096);      // sum | sumsq
    float* scale = alloc(1024);
    float* shift = alloc(1024);
    int* gcnt = (int*)gcntf;
    float* bnsum = bnbuf;
    float* bnsq  = bnbuf + 2048;

    // R1 aliases: xl_bf (6.4MB) dead after k_gather; then h1f/h2f/zb
    ushort_t* xl_bf = (ushort_t*)r1;   // [50000,64] bf16
    float* h1f = r1;                   // [1000,1024]
    float* h2f = r1 + 1048576;         // [1000,512]
    float* zb  = r1 + 1572864;         // [1000,512]

    // R2: CSR buffers during GAT (dead after k_gather), bf16 arena after
    int*   csr_src = (int*)r2;                       // [800000] bytes 0..3.2M
    int*   deg     = (int*)((char*)r2 + 3200000);    // [50000]
    int*   rowptr  = (int*)((char*)r2 + 3400000);    // [50000]
    int*   cursor  = (int*)((char*)r2 + 3600000);    // [50000]
    int*   blocksum= (int*)((char*)r2 + 3800000);    // [196]
    float* csr_w   = (float*)((char*)r2 + 4000000);  // [800000] bytes 4.0M..7.2M

    ushort_t* U = (ushort_t*)r2;       // capacity NN*64*2 = 6,400,000 halves
    ushort_t* cbuf_bf   = U + 0;        // [1000,512]
    ushort_t* pooled_bf = U + 524288;   // [1000,64]
    ushort_t* Wlg_bf    = U + 589824;   // [256,64]
    ushort_t* fpts_bf   = U + 655360;   // [1000,2048]  (dead after gemm1)
    ushort_t* W1_bf     = U + 2703360;  // [1024,2048]  (dead after gemm1)
    ushort_t* W2_bf     = U + 4800512;  // [512,1024]
    ushort_t* h1_bf     = U + 5324800;  // [1000,1024]
    ushort_t* h2_bf     = U + 655360;   // [1000,512]   (reuses fpts region)
    ushort_t* W3_bf     = U + 1200128;  // [256,512]
    ushort_t* Wf_bf     = U + 1331200;  // [512,512]

    // ---- GAT: projection + CSR build + fused gather/pool ----
    k_xl<<<NN / 4, 256, 0, stream>>>(x, Wg, att_src, att_dst, xl_bf, a_src, a_dst);
    hipMemsetAsync(deg, 0, NN * sizeof(int), stream);
    k_deg<<<(NE + 255) / 256, 256, 0, stream>>>(ei, deg);
    k_scan1<<<NB, 256, 0, stream>>>(deg, blocksum);
    k_scan2<<<NB, 256, 0, stream>>>(deg, blocksum, rowptr, cursor);
    k_scatter<<<(NE + 255) / 256, 256, 0, stream>>>(ei, a_src, a_dst, cursor, csr_src, csr_w);
    hipMemsetAsync(gsum, 0, NG * 64 * sizeof(float), stream);
    hipMemsetAsync(gcnt, 0, NG * sizeof(int), stream);
    k_gather<<<NN / 4, 256, 0, stream>>>(csr_src, csr_w, rowptr, deg, xl_bf, a_src, a_dst,
                                         gat_b, batch, gsum, gcnt);
    k_pooled<<<(NG * 64 + 255) / 256, 256, 0, stream>>>(gsum, gcnt, pooled_bf);

    // ---- conversions needed for gnn gemm + gemm1 + gemm2 ----
    k_f2b<<<(GOUTC * 64 + 2047) / 2048, 256, 0, stream>>>(Wlg, Wlg_bf, GOUTC * 64);
    k_f2b<<<(NG * FPC + 2047) / 2048, 256, 0, stream>>>(fpts, fpts_bf, NG * FPC);
    k_f2b<<<(H1C * FPC + 2047) / 2048, 256, 0, stream>>>(W1, W1_bf, H1C * FPC);
    k_f2b<<<(H2C * H1C + 2047) / 2048, 256, 0, stream>>>(W2, W2_bf, H2C * H1C);

    // gnn_out -> cbuf[:, 0:256] (bf16)
    k_mgemm<false, true><<<dim3(GOUTC / 64, 16), 256, 0, stream>>>(
        pooled_bf, Wlg_bf, blg, cbuf_bf, NG, GOUTC, 64, 512);

    // ---- MLP layer 1 ----
    k_mgemm<false, false><<<dim3(H1C / 64, 16), 256, 0, stream>>>(
        fpts_bf, W1_bf, b1, h1f, NG, H1C, FPC, H1C);
    hipMemsetAsync(bnbuf, 0, 4096 * sizeof(float), stream);
    k_bnpart<<<dim3(H1C / 256, 8), 256, 0, stream>>>(h1f, bnsum, bnsq, H1C);
    k_bnfin<<<(H1C + 255) / 256, 256, 0, stream>>>(bnsum, bnsq, g1, be1, scale, shift, H1C);
    k_bnrelu_bf<<<(NG * H1C / 4 + 255) / 256, 256, 0, stream>>>(
        h1f, scale, shift, h1_bf, H1C - 1, NG * H1C);

    // conversions for gemm3/gemmF (fpts/W1 region now dead)
    k_f2b<<<(MOUTC * H2C + 2047) / 2048, 256, 0, stream>>>(W3, W3_bf, MOUTC * H2C);
    k_f2b<<<(D1C * 512 + 2047) / 2048, 256, 0, stream>>>(Wf, Wf_bf, D1C * 512);

    // ---- MLP layer 2 ----
    k_mgemm<false, false><<<dim3(H2C / 64, 16), 256, 0, stream>>>(
        h1_bf, W2_bf, b2, h2f, NG, H2C, H1C, H2C);
    hipMemsetAsync(bnbuf, 0, 4096 * sizeof(float), stream);
    k_bnpart<<<dim3(H2C / 256, 8), 256, 0, stream>>>(h2f, bnsum, bnsq, H2C);
    k_bnfin<<<(H2C + 255) / 256, 256, 0, stream>>>(bnsum, bnsq, g2, be2, scale, shift, H2C);
    k_bnrelu_bf<<<(NG * H2C / 4 + 255) / 256, 256, 0, stream>>>(
        h2f, scale, shift, h2_bf, H2C - 1, NG * H2C);

    // mlp_out -> cbuf[:, 256:512] (bf16)
    k_mgemm<false, true><<<dim3(MOUTC / 64, 16), 256, 0, stream>>>(
        h2_bf, W3_bf, b3, cbuf_bf + 256, NG, MOUTC, H2C, 512);

    // ---- fusion head ----
    k_mgemm<true, false><<<dim3(D1C / 64, 16), 256, 0, stream>>>(
        cbuf_bf, Wf_bf, bf, zb, NG, D1C, GOUTC + MOUTC, D1C);
    hipMemsetAsync(bnbuf, 0, 4096 * sizeof(float), stream);
    k_bnpart<<<dim3(D1C / 256, 8), 256, 0, stream>>>(zb, bnsum, bnsq, D1C);
    k_bnfin<<<(D1C + 255) / 256, 256, 0, stream>>>(bnsum, bnsq, gf, bef, scale, shift, D1C);
    k_final<<<NG, 256, 0, stream>>>(zb, scale, shift, Wl, bl, out);
}

// Round 10
// 420.417 us; speedup vs baseline: 1.3642x; 1.0797x over previous
//
#include <hip/hip_runtime.h>

#define NN 50000
#define NE 800000
#define NG 1000
#define DIN 64
#define HIDC 64
#define GOUTC 256
#define FPC 2048
#define H1C 1024
#define H2C 512
#define MOUTC 256
#define D1C 512
#define EPSV 1e-5f
#define SLOPEV 0.2f
#define NB 196  // ceil(NN/256)

typedef __attribute__((ext_vector_type(8))) short s8v;
typedef __attribute__((ext_vector_type(4))) float f4v;
typedef unsigned short ushort_t;

__device__ inline ushort_t f2b(float f) {
    unsigned u = __builtin_bit_cast(unsigned, f);
    unsigned r = (u + 0x7FFFu + ((u >> 16) & 1u)) >> 16;
    return (ushort_t)r;
}
__device__ inline float b2f(ushort_t u) {
    return __builtin_bit_cast(float, ((unsigned)u) << 16);
}

// ---- GAT: xl_bf = bf16(x @ Wg^T) ; a_src = xl.att_src ; a_dst = xl.att_dst ----
__global__ void k_xl(const float* __restrict__ x, const float* __restrict__ Wg,
                     const float* __restrict__ att_src, const float* __restrict__ att_dst,
                     ushort_t* __restrict__ xl_bf, float* __restrict__ a_src,
                     float* __restrict__ a_dst) {
    __shared__ float Wgs[64][65];
    __shared__ float xs[4][64];
    int t = threadIdx.x;
    int lane = t & 63;
    int w = t >> 6;
    for (int i = t; i < 64 * 64; i += 256) Wgs[i >> 6][i & 63] = Wg[i];
    int node = blockIdx.x * 4 + w;
    xs[w][lane] = x[node * 64 + lane];
    __syncthreads();
    float acc = 0.f;
#pragma unroll
    for (int d = 0; d < 64; ++d) acc += xs[w][d] * Wgs[lane][d];
    xl_bf[node * 64 + lane] = f2b(acc);
    float vs = acc * att_src[lane];
    float vd = acc * att_dst[lane];
#pragma unroll
    for (int off = 32; off > 0; off >>= 1) {
        vs += __shfl_xor(vs, off);
        vd += __shfl_xor(vd, off);
    }
    if (lane == 0) { a_src[node] = vs; a_dst[node] = vd; }
}

// ---- CSR build: degree histogram ----
__global__ void k_deg(const int* __restrict__ ei, int* __restrict__ deg) {
    int e = blockIdx.x * 256 + threadIdx.x;
    if (e < NE) atomicAdd(&deg[ei[NE + e]], 1);
}

// ---- CSR build: hierarchical scan, stage 1: per-block sums ----
__global__ __launch_bounds__(256) void k_scan1(const int* __restrict__ deg,
                                               int* __restrict__ blocksum) {
    int b = blockIdx.x, t = threadIdx.x;
    int idx = b * 256 + t;
    int v = (idx < NN) ? deg[idx] : 0;
#pragma unroll
    for (int off = 32; off > 0; off >>= 1) v += __shfl_xor(v, off);
    __shared__ int ws[4];
    if ((t & 63) == 0) ws[t >> 6] = v;
    __syncthreads();
    if (t == 0) blocksum[b] = ws[0] + ws[1] + ws[2] + ws[3];
}

// ---- CSR build: stage 2: block base + local 256-wide scan -> rowptr/cursor ----
__global__ __launch_bounds__(256) void k_scan2(const int* __restrict__ deg,
                                               const int* __restrict__ blocksum,
                                               int* __restrict__ rowptr,
                                               int* __restrict__ cursor) {
    int b = blockIdx.x, t = threadIdx.x;
    int v = (t < b) ? blocksum[t] : 0;  // NB=196 < 256: one value per thread
#pragma unroll
    for (int off = 32; off > 0; off >>= 1) v += __shfl_xor(v, off);
    __shared__ int ws[4];
    __shared__ int sc[256];
    if ((t & 63) == 0) ws[t >> 6] = v;
    int idx = b * 256 + t;
    int d = (idx < NN) ? deg[idx] : 0;
    sc[t] = d;
    __syncthreads();
    int base = ws[0] + ws[1] + ws[2] + ws[3];
    for (int off = 1; off < 256; off <<= 1) {
        int x = (t >= off) ? sc[t - off] : 0;
        __syncthreads();
        sc[t] += x;
        __syncthreads();
    }
    if (idx < NN) {
        int ex = base + sc[t] - d;  // exclusive prefix
        rowptr[idx] = ex;
        cursor[idx] = ex;
    }
}

// ---- CSR build: scatter packed (src, weight) by dst ----
__global__ void k_scatter(const int* __restrict__ ei, const float* __restrict__ a_src,
                          const float* __restrict__ a_dst, int* __restrict__ cursor,
                          int2* __restrict__ csr_sw) {
    int e = blockIdx.x * 256 + threadIdx.x;
    if (e < NE) {
        int s = ei[e];
        int d = ei[NE + e];
        int pos = atomicAdd(&cursor[d], 1);
        float ev = a_src[s] + a_dst[d];
        ev = ev > 0.f ? ev : SLOPEV * ev;
        int2 v;
        v.x = s;
        v.y = __float_as_int(expf(ev));
        csr_sw[pos] = v;
    }
}

// ---- fused gather: weighted aggregation + bias + relu + mean-pool ----
__global__ void k_gather(const int2* __restrict__ csr_sw, const int* __restrict__ rowptr,
                         const int* __restrict__ deg, const ushort_t* __restrict__ xl_bf,
                         const float* __restrict__ a_src, const float* __restrict__ a_dst,
                         const float* __restrict__ gat_bias, const int* __restrict__ batch,
                         float* __restrict__ gsum, int* __restrict__ gcnt) {
    int t = threadIdx.x, lane = t & 63, w = t >> 6;
    int n = blockIdx.x * 4 + w;
    // self loop
    float ev = a_src[n] + a_dst[n];
    ev = ev > 0.f ? ev : SLOPEV * ev;
    float ex = expf(ev);
    float den = ex;
    float acc = ex * b2f(xl_bf[(size_t)n * 64 + lane]);
    int beg = rowptr[n];
    int end = beg + deg[n];
    int j = beg;
    for (; j + 8 <= end; j += 8) {
        int s[8];
        float wt[8];
#pragma unroll
        for (int u = 0; u < 8; ++u) {
            int2 v = csr_sw[j + u];
            s[u] = v.x;
            wt[u] = __int_as_float(v.y);
        }
        float vv[8];
#pragma unroll
        for (int u = 0; u < 8; ++u) vv[u] = b2f(xl_bf[(size_t)s[u] * 64 + lane]);
#pragma unroll
        for (int u = 0; u < 8; ++u) {
            den += wt[u];
            acc += wt[u] * vv[u];
        }
    }
    for (; j < end; ++j) {
        int2 v = csr_sw[j];
        float wt0 = __int_as_float(v.y);
        den += wt0;
        acc += wt0 * b2f(xl_bf[(size_t)v.x * 64 + lane]);
    }
    float v = acc / den + gat_bias[lane];
    v = v > 0.f ? v : 0.f;
    int b = batch[n];
    atomicAdd(&gsum[b * 64 + lane], v);
    if (lane == 0) atomicAdd(&gcnt[b], 1);
}

__global__ void k_pooled(const float* __restrict__ gsum, const int* __restrict__ gcnt,
                         ushort_t* __restrict__ pooled_bf) {
    int i = blockIdx.x * 256 + threadIdx.x;
    if (i < NG * 64) {
        float c = (float)gcnt[i >> 6];
        pooled_bf[i] = f2b(gsum[i] / fmaxf(c, 1.f));
    }
}

// ---- fp32 -> bf16 conversion, up to 4 segments in one launch ----
// Block b handles seg k where cs[k] <= b < cs[k+1]; 2048 elems per block.
__global__ void k_f2b4(const float* __restrict__ sa, ushort_t* __restrict__ da, int ca,
                       const float* __restrict__ sb, ushort_t* __restrict__ db, int cb,
                       const float* __restrict__ sc_, ushort_t* __restrict__ dc, int cc,
                       const float* __restrict__ sd, ushort_t* __restrict__ dd, int cd,
                       int na, int nb_, int nc, int nd) {
    int b = blockIdx.x;
    const float* s;
    ushort_t* d;
    int lb, n;
    if (b < ca) { s = sa; d = da; lb = b; n = na; }
    else if (b < cb) { s = sb; d = db; lb = b - ca; n = nb_; }
    else if (b < cc) { s = sc_; d = dc; lb = b - cb; n = nc; }
    else { s = sd; d = dd; lb = b - cc; n = nd; }
    int i = (lb * 256 + threadIdx.x) * 8;
    if (i + 8 <= n) {
#pragma unroll
        for (int j = 0; j < 8; ++j) d[i + j] = f2b(s[i + j]);
    } else {
        for (int j = i; j < n; ++j) d[j] = f2b(s[j]);
    }
}

// ---- bf16 MFMA GEMM, BK=64: C[M,N](ldc) = A[M,K]bf16 @ B[N,K]bf16^T + bias ----
template <bool RELU, bool OBF16>
__global__ __launch_bounds__(256) void k_mgemm(const ushort_t* __restrict__ A,
                                               const ushort_t* __restrict__ B,
                                               const float* __restrict__ bias, void* Cv,
                                               int M, int N, int K, int ldc) {
    __shared__ ushort_t As[64][68];
    __shared__ ushort_t Bs[64][68];
    int t = threadIdx.x;
    int lane = t & 63, w = t >> 6;
    int wr = w >> 1, wc = w & 1;
    int bm = blockIdx.y * 64, bn = blockIdx.x * 64;
    f4v acc[2][2];
#pragma unroll
    for (int m = 0; m < 2; ++m)
#pragma unroll
        for (int n = 0; n < 2; ++n) acc[m][n] = (f4v){0.f, 0.f, 0.f, 0.f};

    int lr = t >> 2;           // row 0..63
    int lk = (t & 3) * 16;     // 0,16,32,48 halves
    int arow = bm + lr;
    bool aval = arow < M;
    const ushort_t* aptr = A + (size_t)(aval ? arow : (M - 1)) * K + lk;
    const ushort_t* bptr = B + (size_t)(bn + lr) * K + lk;
    int fr = lane & 15, kg = lane >> 4;

    for (int k0 = 0; k0 < K; k0 += 64) {
        s8v av0 = {}, av1 = {};
        if (aval) {
            av0 = *(const s8v*)(aptr + k0);
            av1 = *(const s8v*)(aptr + k0 + 8);
        }
        s8v bv0 = *(const s8v*)(bptr + k0);
        s8v bv1 = *(const s8v*)(bptr + k0 + 8);
        *(s8v*)&As[lr][lk] = av0;
        *(s8v*)&As[lr][lk + 8] = av1;
        *(s8v*)&Bs[lr][lk] = bv0;
        *(s8v*)&Bs[lr][lk + 8] = bv1;
        __syncthreads();
#pragma unroll
        for (int kk = 0; kk < 2; ++kk) {
            s8v b0 = *(const s8v*)&Bs[wc * 32 + fr][kk * 32 + kg * 8];
            s8v b1 = *(const s8v*)&Bs[wc * 32 + 16 + fr][kk * 32 + kg * 8];
#pragma unroll
            for (int m = 0; m < 2; ++m) {
                s8v af = *(const s8v*)&As[wr * 32 + m * 16 + fr][kk * 32 + kg * 8];
                acc[m][0] = __builtin_amdgcn_mfma_f32_16x16x32_bf16(af, b0, acc[m][0], 0, 0, 0);
                acc[m][1] = __builtin_amdgcn_mfma_f32_16x16x32_bf16(af, b1, acc[m][1], 0, 0, 0);
            }
        }
        __syncthreads();
    }
    int fq = lane >> 4;
#pragma unroll
    for (int m = 0; m < 2; ++m) {
        int row = bm + wr * 32 + m * 16 + fq * 4;
#pragma unroll
        for (int n = 0; n < 2; ++n) {
            int col = bn + wc * 32 + n * 16 + fr;
            float bb = bias[col];
#pragma unroll
            for (int r = 0; r < 4; ++r) {
                int gr = row + r;
                if (gr < M) {
                    float v = acc[m][n][r] + bb;
                    if (RELU) v = fmaxf(v, 0.f);
                    if (OBF16) ((ushort_t*)Cv)[(size_t)gr * ldc + col] = f2b(v);
                    else ((float*)Cv)[(size_t)gr * ldc + col] = v;
                }
            }
        }
    }
}

// ---- BN: row-split partial sums (atomic) ----
__global__ void k_bnpart(const float* __restrict__ h, float* __restrict__ sum,
                         float* __restrict__ sumsq, int ncols) {
    int col = blockIdx.x * 256 + threadIdx.x;
    int r0 = blockIdx.y * 125;
    float s = 0.f, q = 0.f;
    for (int r = r0; r < r0 + 125; ++r) {
        float v = h[(size_t)r * ncols + col];
        s += v;
        q += v * v;
    }
    atomicAdd(&sum[col], s);
    atomicAdd(&sumsq[col], q);
}

// ---- BN normalize (+stats finalize inline) + relu + bf16 ----
__global__ void k_bnrelu_bf(const float* __restrict__ h, const float* __restrict__ sum,
                            const float* __restrict__ sumsq, const float* __restrict__ gamma,
                            const float* __restrict__ beta, ushort_t* __restrict__ dst,
                            int colmask, int total) {
    int i = (blockIdx.x * 256 + threadIdx.x) * 4;
    if (i < total) {
#pragma unroll
        for (int j = 0; j < 4; ++j) {
            int col = (i + j) & colmask;
            float mu = sum[col] * (1.f / NG);
            float var = sumsq[col] * (1.f / NG) - mu * mu;
            float sc = gamma[col] * rsqrtf(var + EPSV);
            float sh = beta[col] - mu * sc;
            float v = h[i + j] * sc + sh;
            dst[i + j] = f2b(fmaxf(v, 0.f));
        }
    }
}

// ---- final: out[g] = sum_j (bn(z[g,j])) * Wl[j] + bl (stats finalize inline) ----
__global__ void k_final(const float* __restrict__ z, const float* __restrict__ sum,
                        const float* __restrict__ sumsq, const float* __restrict__ gamma,
                        const float* __restrict__ beta, const float* __restrict__ Wl,
                        const float* __restrict__ bl, float* __restrict__ out) {
    int g = blockIdx.x;
    int t = threadIdx.x;
    float acc = 0.f;
    for (int j = t; j < D1C; j += 256) {
        float mu = sum[j] * (1.f / NG);
        float var = sumsq[j] * (1.f / NG) - mu * mu;
        float sc = gamma[j] * rsqrtf(var + EPSV);
        float sh = beta[j] - mu * sc;
        float v = z[g * D1C + j] * sc + sh;
        acc += v * Wl[j];
    }
#pragma unroll
    for (int off = 32; off > 0; off >>= 1) acc += __shfl_xor(acc, off);
    __shared__ float red[4];
    int lane = t & 63, w = t >> 6;
    if (lane == 0) red[w] = acc;
    __syncthreads();
    if (t == 0) out[g] = red[0] + red[1] + red[2] + red[3] + bl[0];
}

extern "C" void kernel_launch(void* const* d_in, const int* in_sizes, int n_in,
                              void* d_out, int out_size, void* d_ws, size_t ws_size,
                              hipStream_t stream) {
    const float* x       = (const float*)d_in[0];
    const int*   ei      = (const int*)d_in[1];
    const int*   batch   = (const int*)d_in[2];
    const float* fpts    = (const float*)d_in[3];
    const float* Wg      = (const float*)d_in[4];
    const float* att_src = (const float*)d_in[5];
    const float* att_dst = (const float*)d_in[6];
    const float* gat_b   = (const float*)d_in[7];
    const float* Wlg     = (const float*)d_in[8];
    const float* blg     = (const float*)d_in[9];
    const float* W1      = (const float*)d_in[10];
    const float* b1      = (const float*)d_in[11];
    const float* g1      = (const float*)d_in[12];
    const float* be1     = (const float*)d_in[13];
    const float* W2      = (const float*)d_in[14];
    const float* b2      = (const float*)d_in[15];
    const float* g2      = (const float*)d_in[16];
    const float* be2     = (const float*)d_in[17];
    const float* W3      = (const float*)d_in[18];
    const float* b3      = (const float*)d_in[19];
    const float* Wf      = (const float*)d_in[20];
    const float* bf      = (const float*)d_in[21];
    const float* gf      = (const float*)d_in[22];
    const float* bef     = (const float*)d_in[23];
    const float* Wl      = (const float*)d_in[24];
    const float* bl      = (const float*)d_in[25];
    float* out = (float*)d_out;

    size_t o = 0;
    auto alloc = [&](size_t nfloats) {
        float* p = (float*)((char*)d_ws + o);
        o += ((nfloats * sizeof(float) + 255) / 256) * 256;
        return p;
    };
    float* r1    = alloc(NN * 64);   // region R1: xl_bf during GAT; h1f/h2f/zb after
    float* r2    = alloc(NN * 64);   // region R2: CSR during GAT; bf16 arena after
    float* a_src = alloc(NN);
    float* a_dst = alloc(NN);
    float* gsum  = alloc(NG * 64);
    float* gcntf = alloc(NG);
    float* bnbuf = alloc(4096);      // sum | sumsq
    int* gcnt = (int*)gcntf;
    float* bnsum = bnbuf;
    float* bnsq  = bnbuf + 2048;

    // R1 aliases: xl_bf (6.4MB) dead after k_gather; then h1f/h2f/zb
    ushort_t* xl_bf = (ushort_t*)r1;   // [50000,64] bf16
    float* h1f = r1;                   // [1000,1024]
    float* h2f = r1 + 1048576;         // [1000,512]
    float* zb  = r1 + 1572864;         // [1000,512]

    // R2: CSR buffers during GAT (dead after k_gather), bf16 arena after
    int2*  csr_sw  = (int2*)r2;                      // [800000] int2, bytes 0..6.4M
    int*   deg     = (int*)((char*)r2 + 6400000);    // [50000]
    int*   rowptr  = (int*)((char*)r2 + 6600000);    // [50000]
    int*   cursor  = (int*)((char*)r2 + 6800000);    // [50000]
    int*   blocksum= (int*)((char*)r2 + 7000000);    // [196]

    ushort_t* U = (ushort_t*)r2;       // capacity NN*64*2 = 6,400,000 halves
    ushort_t* cbuf_bf   = U + 0;        // [1000,512]
    ushort_t* pooled_bf = U + 524288;   // [1000,64]
    ushort_t* Wlg_bf    = U + 589824;   // [256,64]
    ushort_t* fpts_bf   = U + 655360;   // [1000,2048]  (dead after gemm1)
    ushort_t* W1_bf     = U + 2703360;  // [1024,2048]  (dead after gemm1)
    ushort_t* W2_bf     = U + 4800512;  // [512,1024]
    ushort_t* h1_bf     = U + 5324800;  // [1000,1024]
    ushort_t* h2_bf     = U + 655360;   // [1000,512]   (reuses fpts region)
    ushort_t* W3_bf     = U + 1200128;  // [256,512]
    ushort_t* Wf_bf     = U + 1331200;  // [512,512]

    // ---- GAT: projection + CSR build + fused gather/pool ----
    k_xl<<<NN / 4, 256, 0, stream>>>(x, Wg, att_src, att_dst, xl_bf, a_src, a_dst);
    hipMemsetAsync(deg, 0, NN * sizeof(int), stream);
    k_deg<<<(NE + 255) / 256, 256, 0, stream>>>(ei, deg);
    k_scan1<<<NB, 256, 0, stream>>>(deg, blocksum);
    k_scan2<<<NB, 256, 0, stream>>>(deg, blocksum, rowptr, cursor);
    k_scatter<<<(NE + 255) / 256, 256, 0, stream>>>(ei, a_src, a_dst, cursor, csr_sw);
    hipMemsetAsync(gsum, 0, NG * 64 * sizeof(float), stream);
    hipMemsetAsync(gcnt, 0, NG * sizeof(int), stream);
    k_gather<<<NN / 4, 256, 0, stream>>>(csr_sw, rowptr, deg, xl_bf, a_src, a_dst,
                                         gat_b, batch, gsum, gcnt);
    k_pooled<<<(NG * 64 + 255) / 256, 256, 0, stream>>>(gsum, gcnt, pooled_bf);

    // ---- conversions for gnn gemm + gemm1 + gemm2 (one launch) ----
    {
        int ba = GOUTC * 64 / 2048;            // 8
        int bb = ba + NG * FPC / 2048;         // +1000
        int bc = bb + H1C * FPC / 2048;        // +1024
        int bd = bc + H2C * H1C / 2048;        // +256
        k_f2b4<<<bd, 256, 0, stream>>>(Wlg, Wlg_bf, ba, fpts, fpts_bf, bb,
                                       W1, W1_bf, bc, W2, W2_bf, bd,
                                       GOUTC * 64, NG * FPC, H1C * FPC, H2C * H1C);
    }

    // gnn_out -> cbuf[:, 0:256] (bf16)
    k_mgemm<false, true><<<dim3(GOUTC / 64, 16), 256, 0, stream>>>(
        pooled_bf, Wlg_bf, blg, cbuf_bf, NG, GOUTC, 64, 512);

    // ---- MLP layer 1 ----
    k_mgemm<false, false><<<dim3(H1C / 64, 16), 256, 0, stream>>>(
        fpts_bf, W1_bf, b1, h1f, NG, H1C, FPC, H1C);
    hipMemsetAsync(bnbuf, 0, 4096 * sizeof(float), stream);
    k_bnpart<<<dim3(H1C / 256, 8), 256, 0, stream>>>(h1f, bnsum, bnsq, H1C);
    k_bnrelu_bf<<<(NG * H1C / 4 + 255) / 256, 256, 0, stream>>>(
        h1f, bnsum, bnsq, g1, be1, h1_bf, H1C - 1, NG * H1C);

    // conversions for gemm3/gemmF (fpts/W1 region now dead)
    {
        int ba = MOUTC * H2C / 2048;           // 64
        int bb = ba + D1C * 512 / 2048;        // +128
        k_f2b4<<<bb, 256, 0, stream>>>(W3, W3_bf, ba, Wf, Wf_bf, bb,
                                       (const float*)0, (ushort_t*)0, bb,
                                       (const float*)0, (ushort_t*)0, bb,
                                       MOUTC * H2C, D1C * 512, 0, 0);
    }

    // ---- MLP layer 2 ----
    k_mgemm<false, false><<<dim3(H2C / 64, 16), 256, 0, stream>>>(
        h1_bf, W2_bf, b2, h2f, NG, H2C, H1C, H2C);
    hipMemsetAsync(bnbuf, 0, 4096 * sizeof(float), stream);
    k_bnpart<<<dim3(H2C / 256, 8), 256, 0, stream>>>(h2f, bnsum, bnsq, H2C);
    k_bnrelu_bf<<<(NG * H2C / 4 + 255) / 256, 256, 0, stream>>>(
        h2f, bnsum, bnsq, g2, be2, h2_bf, H2C - 1, NG * H2C);

    // mlp_out -> cbuf[:, 256:512] (bf16)
    k_mgemm<false, true><<<dim3(MOUTC / 64, 16), 256, 0, stream>>>(
        h2_bf, W3_bf, b3, cbuf_bf + 256, NG, MOUTC, H2C, 512);

    // ---- fusion head ----
    k_mgemm<true, false><<<dim3(D1C / 64, 16), 256, 0, stream>>>(
        cbuf_bf, Wf_bf, bf, zb, NG, D1C, GOUTC + MOUTC, D1C);
    hipMemsetAsync(bnbuf, 0, 4096 * sizeof(float), stream);
    k_bnpart<<<dim3(D1C / 256, 8), 256, 0, stream>>>(zb, bnsum, bnsq, D1C);
    k_final<<<NG, 256, 0, stream>>>(zb, bnsum, bnsq, gf, bef, Wl, bl, out);
}